// Round 1
// baseline (591.853 us; speedup 1.0000x reference)
//
#include <hip/hip_runtime.h>
#include <hip/hip_bf16.h>

#define N_NODES 8000
#define D_IN    2048
#define NE      100000
#define H_DIM   64

typedef __attribute__((ext_vector_type(8))) short bf16x8;
typedef __attribute__((ext_vector_type(4))) float f32x4;

__device__ inline unsigned short f2bf(float f) {
  union { float f; unsigned u; } v; v.f = f;
  unsigned r = v.u + 0x7fffu + ((v.u >> 16) & 1u);   // round-to-nearest-even
  return (unsigned short)(r >> 16);
}

// ---- cast X (fp32 -> bf16), 4 elems/thread -------------------------------
__global__ void cast_x_kernel(const float* __restrict__ x,
                              unsigned short* __restrict__ y, int n4) {
  int i = blockIdx.x * 256 + threadIdx.x;
  if (i >= n4) return;
  float4 v = reinterpret_cast<const float4*>(x)[i];
  ushort4 o;
  o.x = f2bf(v.x); o.y = f2bf(v.y); o.z = f2bf(v.z); o.w = f2bf(v.w);
  reinterpret_cast<ushort4*>(y)[i] = o;
}

// ---- pack W_pb/W_nb into transposed bf16 [256 cols][2048 k] ---------------
// cols 0:64   = W_pb rows 0:2048    (pos agg part)
// cols 64:128 = W_pb rows 2048:4096 (pos self part)
// cols 128:192= W_nb rows 0:2048    (neg agg part)
// cols 192:256= W_nb rows 2048:4096 (neg self part)
__global__ void packw_kernel(const float* __restrict__ Wpb,
                             const float* __restrict__ Wnb,
                             unsigned short* __restrict__ WT) {
  int idx = blockIdx.x * 256 + threadIdx.x;   // = c*2048 + k
  int c = idx >> 11;
  int k = idx & 2047;
  const float* W = (c < 128) ? Wpb : Wnb;
  int cc = c & 63;
  int kk = (c & 64) ? (2048 + k) : k;
  WT[idx] = f2bf(W[(size_t)kk * 64 + cc]);
}

// ---- GEMM1: Y[8000][256] = X_bf16 [8000][2048] @ Wpack ---------------------
// block = 256 thr (4 waves), tile 64 rows x 64 cols; wave w -> rows w*16..+16
__global__ void gemm1_kernel(const unsigned short* __restrict__ Xb,
                             const unsigned short* __restrict__ WT,
                             float* __restrict__ Y) {
  int wave = threadIdx.x >> 6;
  int lane = threadIdx.x & 63;
  int row0 = blockIdx.x * 64 + wave * 16;
  int col0 = blockIdx.y * 64;
  int lrow = lane & 15;
  int koff = (lane >> 4) * 8;
  f32x4 acc[4] = {};
  const unsigned short* Ap  = Xb + (size_t)(row0 + lrow) * D_IN + koff;
  const unsigned short* Bp0 = WT + (size_t)(col0 + lrow) * D_IN + koff;
  for (int k0 = 0; k0 < D_IN; k0 += 32) {
    bf16x8 a = *reinterpret_cast<const bf16x8*>(Ap + k0);
#pragma unroll
    for (int c = 0; c < 4; ++c) {
      bf16x8 b = *reinterpret_cast<const bf16x8*>(Bp0 + (size_t)c * 16 * D_IN + k0);
      acc[c] = __builtin_amdgcn_mfma_f32_16x16x32_bf16(a, b, acc[c], 0, 0, 0);
    }
  }
  int crow = row0 + (lane >> 4) * 4;
  int ccol = col0 + (lane & 15);
#pragma unroll
  for (int c = 0; c < 4; ++c)
#pragma unroll
    for (int r = 0; r < 4; ++r)
      Y[(size_t)(crow + r) * 256 + ccol + c * 16] = acc[c][r];
}

// ---- base scatter: aggP += Y[col,0:64] over pos edges; aggN over neg ------
__global__ void base_scatter_kernel(const float* __restrict__ Y,
                                    const int* __restrict__ pe,
                                    const int* __restrict__ ne,
                                    float* __restrict__ aggP, float* __restrict__ aggN,
                                    float* __restrict__ cntP, float* __restrict__ cntN) {
  int t = blockIdx.x * 256 + threadIdx.x;
  int e = t >> 6;
  int d = t & 63;
  if (e >= 2 * NE) return;
  bool pos = e < NE;
  const int* edges = pos ? pe : ne;
  int ei = pos ? e : e - NE;
  int row = edges[ei];
  int col = edges[NE + ei];
  float v = Y[(size_t)col * 256 + (pos ? 0 : 128) + d];
  atomicAdd((pos ? aggP : aggN) + (size_t)row * 64 + d, v);
  if (d == 0) atomicAdd((pos ? cntP : cntN) + row, 1.0f);
}

// ---- base finish: H1[n] = [tanh(l2norm(pre_pos)) | tanh(l2norm(pre_neg))] -
__global__ void base_finish_kernel(const float* __restrict__ Y,
                                   const float* __restrict__ aggP, const float* __restrict__ aggN,
                                   const float* __restrict__ cntP, const float* __restrict__ cntN,
                                   const float* __restrict__ bpb, const float* __restrict__ bnb,
                                   float* __restrict__ H1) {
  int n = blockIdx.x;
  int t = threadIdx.x;          // 0..127 ; wave0 = pos, wave1 = neg
  int w = t >> 6;
  int d = t & 63;
  float pre;
  if (w == 0)
    pre = aggP[(size_t)n * 64 + d] / fmaxf(cntP[n], 1.0f) + Y[(size_t)n * 256 + 64 + d] + bpb[d];
  else
    pre = aggN[(size_t)n * 64 + d] / fmaxf(cntN[n], 1.0f) + Y[(size_t)n * 256 + 192 + d] + bnb[d];
  float ss = pre * pre;
#pragma unroll
  for (int o = 32; o > 0; o >>= 1) ss += __shfl_xor(ss, o);
  H1[(size_t)n * 128 + t] = tanhf(pre / fmaxf(sqrtf(ss), 1e-12f));
}

// ---- deep scatter: Sp[row] += H1[col] (pos edges); Sn (neg edges) ----------
__global__ void deep_scatter_kernel(const float* __restrict__ H1,
                                    const int* __restrict__ pe,
                                    const int* __restrict__ ne,
                                    float* __restrict__ Sp, float* __restrict__ Sn) {
  int t = blockIdx.x * 256 + threadIdx.x;
  int e = t >> 7;
  int d = t & 127;
  if (e >= 2 * NE) return;
  bool pos = e < NE;
  const int* edges = pos ? pe : ne;
  int ei = pos ? e : e - NE;
  int row = edges[ei];
  int col = edges[NE + ei];
  atomicAdd((pos ? Sp : Sn) + (size_t)row * 128 + d, H1[(size_t)col * 128 + d]);
}

// ---- deep finish: tiny GEMV + l2norm + tanh + final z-l2norm ---------------
__global__ void deep_finish_kernel(const float* __restrict__ H1,
                                   const float* __restrict__ Sp, const float* __restrict__ Sn,
                                   const float* __restrict__ cntP, const float* __restrict__ cntN,
                                   const float* __restrict__ Wpd, const float* __restrict__ bpd,
                                   const float* __restrict__ Wnd, const float* __restrict__ bnd,
                                   float* __restrict__ Xmol, unsigned short* __restrict__ Xmb) {
  int n = blockIdx.x;
  int t = threadIdx.x;          // 0..127 ; wave0 computes h_pos2, wave1 h_neg2
  int w = t >> 6;
  int lane = t & 63;
  __shared__ float sh_op[128], sh_on[128], sh_h[128], sh_ss[2];
  float icp = 1.0f / (cntP[n] + 1.0f);
  float icn = 1.0f / (cntN[n] + 1.0f);
  float hv = H1[(size_t)n * 128 + t];
  sh_h[t]  = hv;
  sh_op[t] = (Sp[(size_t)n * 128 + t] + hv) * icp;   // mean incl. self-loop
  sh_on[t] = (Sn[(size_t)n * 128 + t] + hv) * icn;
  __syncthreads();
  const float* W = w ? Wnd : Wpd;
  float pre = (w ? bnd : bpd)[lane];
  int o1b = w ? 64 : 0;   // pos-deep o1 = scatter(h_pos over pos) ; neg-deep o1 = scatter(h_neg over pos)
  int o2b = w ? 0 : 64;   // pos-deep o2 = scatter(h_neg over neg) ; neg-deep o2 = scatter(h_pos over neg)
  for (int k = 0; k < 64; ++k) pre += sh_op[o1b + k] * W[k * 64 + lane];
  for (int k = 0; k < 64; ++k) pre += sh_on[o2b + k] * W[(64 + k) * 64 + lane];
  for (int k = 0; k < 64; ++k) pre += sh_h[w * 64 + k] * W[(128 + k) * 64 + lane];
  float ss = pre * pre;
#pragma unroll
  for (int o = 32; o > 0; o >>= 1) ss += __shfl_xor(ss, o);
  float tv = tanhf(pre / fmaxf(sqrtf(ss), 1e-12f));
  float ts = tv * tv;
#pragma unroll
  for (int o = 32; o > 0; o >>= 1) ts += __shfl_xor(ts, o);
  if (lane == 0) sh_ss[w] = ts;
  __syncthreads();
  float xm = tv / fmaxf(sqrtf(sh_ss[0] + sh_ss[1]), 1e-12f);
  Xmol[(size_t)n * 128 + t] = xm;
  Xmb[(size_t)n * 128 + t]  = f2bf(xm);
}

// ---- pred: (Xm @ Xm^T)*mask, write 64M preds, accumulate loss --------------
__global__ void pred_kernel(const unsigned short* __restrict__ Xmb,
                            const float* __restrict__ mask,
                            const float* __restrict__ labels,
                            float* __restrict__ pred, float* __restrict__ lossAcc) {
  int wave = threadIdx.x >> 6;
  int lane = threadIdx.x & 63;
  int row0 = blockIdx.x * 64 + wave * 16;
  int col0 = blockIdx.y * 64;
  int lrow = lane & 15;
  int koff = (lane >> 4) * 8;
  f32x4 acc[4] = {};
  const unsigned short* Ap = Xmb + (size_t)(row0 + lrow) * 128 + koff;
  const unsigned short* Bp = Xmb + (size_t)(col0 + lrow) * 128 + koff;
#pragma unroll
  for (int k0 = 0; k0 < 128; k0 += 32) {
    bf16x8 a = *reinterpret_cast<const bf16x8*>(Ap + k0);
#pragma unroll
    for (int c = 0; c < 4; ++c) {
      bf16x8 b = *reinterpret_cast<const bf16x8*>(Bp + (size_t)c * 16 * 128 + k0);
      acc[c] = __builtin_amdgcn_mfma_f32_16x16x32_bf16(a, b, acc[c], 0, 0, 0);
    }
  }
  float local = 0.0f;
  int crow = row0 + (lane >> 4) * 4;
  int ccol = col0 + (lane & 15);
#pragma unroll
  for (int c = 0; c < 4; ++c)
#pragma unroll
    for (int r = 0; r < 4; ++r) {
      size_t idx = (size_t)(crow + r) * N_NODES + ccol + c * 16;
      float m = mask[idx];
      float p = acc[c][r] * m;
      pred[idx] = p;
      float dd = p - labels[idx];
      local += dd * dd;
    }
#pragma unroll
  for (int o = 32; o > 0; o >>= 1) local += __shfl_xor(local, o);
  __shared__ float red[4];
  if (lane == 0) red[wave] = local;
  __syncthreads();
  if (threadIdx.x == 0) atomicAdd(lossAcc, red[0] + red[1] + red[2] + red[3]);
}

__global__ void loss_final_kernel(const float* __restrict__ lossAcc, float* __restrict__ out0) {
  out0[0] = lossAcc[0] * (1.0f / ((float)N_NODES * (float)N_NODES));
}

extern "C" void kernel_launch(void* const* d_in, const int* in_sizes, int n_in,
                              void* d_out, int out_size, void* d_ws, size_t ws_size,
                              hipStream_t stream) {
  const float* X      = (const float*)d_in[0];
  const int*   pe     = (const int*)d_in[1];
  const int*   ne     = (const int*)d_in[2];
  const float* labels = (const float*)d_in[3];
  const float* mask   = (const float*)d_in[4];
  const float* Wpb    = (const float*)d_in[5];
  const float* bpb    = (const float*)d_in[6];
  const float* Wnb    = (const float*)d_in[7];
  const float* bnb    = (const float*)d_in[8];
  const float* Wpd    = (const float*)d_in[9];
  const float* bpd    = (const float*)d_in[10];
  const float* Wnd    = (const float*)d_in[11];
  const float* bnd    = (const float*)d_in[12];

  float* out      = (float*)d_out;
  float* out_xmol = out + 1;
  float* out_pred = out + 1 + (size_t)N_NODES * 128;

  char* ws = (char*)d_ws;
  size_t off = 0;
  float* Y = (float*)(ws + off);      off += (size_t)N_NODES * 256 * 4;
  char* zstart = ws + off;
  float* aggP = (float*)(ws + off);   off += (size_t)N_NODES * 64 * 4;
  float* aggN = (float*)(ws + off);   off += (size_t)N_NODES * 64 * 4;
  float* cntP = (float*)(ws + off);   off += (size_t)N_NODES * 4;
  float* cntN = (float*)(ws + off);   off += (size_t)N_NODES * 4;
  float* Sp   = (float*)(ws + off);   off += (size_t)N_NODES * 128 * 4;
  float* Sn   = (float*)(ws + off);   off += (size_t)N_NODES * 128 * 4;
  float* lossAcc = (float*)(ws + off); off += 256;
  size_t zsize = (size_t)((ws + off) - zstart);
  unsigned short* Xb  = (unsigned short*)(ws + off); off += (size_t)N_NODES * D_IN * 2;
  unsigned short* WT  = (unsigned short*)(ws + off); off += (size_t)256 * 2048 * 2;
  unsigned short* Xmb = (unsigned short*)(ws + off); off += (size_t)N_NODES * 128 * 2;
  float* H1 = (float*)(ws + off);     off += (size_t)N_NODES * 128 * 4;

  hipMemsetAsync(zstart, 0, zsize, stream);
  cast_x_kernel<<<16000, 256, 0, stream>>>(X, Xb, N_NODES * D_IN / 4);
  packw_kernel<<<2048, 256, 0, stream>>>(Wpb, Wnb, WT);
  gemm1_kernel<<<dim3(125, 4), 256, 0, stream>>>(Xb, WT, Y);
  base_scatter_kernel<<<(2 * NE * 64) / 256, 256, 0, stream>>>(Y, pe, ne, aggP, aggN, cntP, cntN);
  base_finish_kernel<<<N_NODES, 128, 0, stream>>>(Y, aggP, aggN, cntP, cntN, bpb, bnb, H1);
  deep_scatter_kernel<<<(2 * NE * 128) / 256, 256, 0, stream>>>(H1, pe, ne, Sp, Sn);
  deep_finish_kernel<<<N_NODES, 128, 0, stream>>>(H1, Sp, Sn, cntP, cntN, Wpd, bpd, Wnd, bnd,
                                                  out_xmol, Xmb);
  pred_kernel<<<dim3(125, 125), 256, 0, stream>>>(Xmb, mask, labels, out_pred, lossAcc);
  loss_final_kernel<<<1, 1, 0, stream>>>(lossAcc, out);
}

// Round 3
// 544.697 us; speedup vs baseline: 1.0866x; 1.0866x over previous
//
#include <hip/hip_runtime.h>
#include <hip/hip_bf16.h>

#define N_NODES 8000
#define D_IN    2048
#define NE      100000
#define H_DIM   64

typedef __attribute__((ext_vector_type(8))) short bf16x8;
typedef __attribute__((ext_vector_type(4))) float f32x4;

__device__ inline unsigned short f2bf(float f) {
  union { float f; unsigned u; } v; v.f = f;
  unsigned r = v.u + 0x7fffu + ((v.u >> 16) & 1u);   // round-to-nearest-even
  return (unsigned short)(r >> 16);
}

// ---- cast X (fp32 -> bf16), 4 elems/thread -------------------------------
__global__ void cast_x_kernel(const float* __restrict__ x,
                              unsigned short* __restrict__ y, int n4) {
  int i = blockIdx.x * 256 + threadIdx.x;
  if (i >= n4) return;
  float4 v = reinterpret_cast<const float4*>(x)[i];
  ushort4 o;
  o.x = f2bf(v.x); o.y = f2bf(v.y); o.z = f2bf(v.z); o.w = f2bf(v.w);
  reinterpret_cast<ushort4*>(y)[i] = o;
}

// ---- pack W_pb/W_nb into transposed bf16 [256 cols][2048 k] ---------------
__global__ void packw_kernel(const float* __restrict__ Wpb,
                             const float* __restrict__ Wnb,
                             unsigned short* __restrict__ WT) {
  int idx = blockIdx.x * 256 + threadIdx.x;   // = c*2048 + k
  int c = idx >> 11;
  int k = idx & 2047;
  const float* W = (c < 128) ? Wpb : Wnb;
  int cc = c & 63;
  int kk = (c & 64) ? (2048 + k) : k;
  WT[idx] = f2bf(W[(size_t)kk * 64 + cc]);
}

// ---- GEMM1: Y[8000][256] = X_bf16 [8000][2048] @ Wpack ---------------------
__global__ void gemm1_kernel(const unsigned short* __restrict__ Xb,
                             const unsigned short* __restrict__ WT,
                             float* __restrict__ Y) {
  int wave = threadIdx.x >> 6;
  int lane = threadIdx.x & 63;
  int row0 = blockIdx.x * 64 + wave * 16;
  int col0 = blockIdx.y * 64;
  int lrow = lane & 15;
  int koff = (lane >> 4) * 8;
  f32x4 acc[4] = {};
  const unsigned short* Ap  = Xb + (size_t)(row0 + lrow) * D_IN + koff;
  const unsigned short* Bp0 = WT + (size_t)(col0 + lrow) * D_IN + koff;
  for (int k0 = 0; k0 < D_IN; k0 += 32) {
    bf16x8 a = *reinterpret_cast<const bf16x8*>(Ap + k0);
#pragma unroll
    for (int c = 0; c < 4; ++c) {
      bf16x8 b = *reinterpret_cast<const bf16x8*>(Bp0 + (size_t)c * 16 * D_IN + k0);
      acc[c] = __builtin_amdgcn_mfma_f32_16x16x32_bf16(a, b, acc[c], 0, 0, 0);
    }
  }
  int crow = row0 + (lane >> 4) * 4;
  int ccol = col0 + (lane & 15);
#pragma unroll
  for (int c = 0; c < 4; ++c)
#pragma unroll
    for (int r = 0; r < 4; ++r)
      Y[(size_t)(crow + r) * 256 + ccol + c * 16] = acc[c][r];
}

// ---- base scatter: aggP += Y[col,0:64] over pos edges; aggN over neg ------
__global__ void base_scatter_kernel(const float* __restrict__ Y,
                                    const int* __restrict__ pe,
                                    const int* __restrict__ ne,
                                    float* __restrict__ aggP, float* __restrict__ aggN,
                                    float* __restrict__ cntP, float* __restrict__ cntN) {
  int t = blockIdx.x * 256 + threadIdx.x;
  int e = t >> 6;
  int d = t & 63;
  if (e >= 2 * NE) return;
  bool pos = e < NE;
  const int* edges = pos ? pe : ne;
  int ei = pos ? e : e - NE;
  int row = edges[ei];
  int col = edges[NE + ei];
  float v = Y[(size_t)col * 256 + (pos ? 0 : 128) + d];
  atomicAdd((pos ? aggP : aggN) + (size_t)row * 64 + d, v);
  if (d == 0) atomicAdd((pos ? cntP : cntN) + row, 1.0f);
}

// ---- base finish: H1[n] = [tanh(l2norm(pre_pos)) | tanh(l2norm(pre_neg))] -
__global__ void base_finish_kernel(const float* __restrict__ Y,
                                   const float* __restrict__ aggP, const float* __restrict__ aggN,
                                   const float* __restrict__ cntP, const float* __restrict__ cntN,
                                   const float* __restrict__ bpb, const float* __restrict__ bnb,
                                   float* __restrict__ H1) {
  int n = blockIdx.x;
  int t = threadIdx.x;          // 0..127 ; wave0 = pos, wave1 = neg
  int w = t >> 6;
  int d = t & 63;
  float pre;
  if (w == 0)
    pre = aggP[(size_t)n * 64 + d] / fmaxf(cntP[n], 1.0f) + Y[(size_t)n * 256 + 64 + d] + bpb[d];
  else
    pre = aggN[(size_t)n * 64 + d] / fmaxf(cntN[n], 1.0f) + Y[(size_t)n * 256 + 192 + d] + bnb[d];
  float ss = pre * pre;
#pragma unroll
  for (int o = 32; o > 0; o >>= 1) ss += __shfl_xor(ss, o);
  H1[(size_t)n * 128 + t] = tanhf(pre / fmaxf(sqrtf(ss), 1e-12f));
}

// ---- deep scatter: Sp[row] += H1[col] (pos edges); Sn (neg edges) ----------
__global__ void deep_scatter_kernel(const float* __restrict__ H1,
                                    const int* __restrict__ pe,
                                    const int* __restrict__ ne,
                                    float* __restrict__ Sp, float* __restrict__ Sn) {
  int t = blockIdx.x * 256 + threadIdx.x;
  int e = t >> 7;
  int d = t & 127;
  if (e >= 2 * NE) return;
  bool pos = e < NE;
  const int* edges = pos ? pe : ne;
  int ei = pos ? e : e - NE;
  int row = edges[ei];
  int col = edges[NE + ei];
  atomicAdd((pos ? Sp : Sn) + (size_t)row * 128 + d, H1[(size_t)col * 128 + d]);
}

// ---- deep finish: tiny GEMV + l2norm + tanh + final z-l2norm ---------------
__global__ void deep_finish_kernel(const float* __restrict__ H1,
                                   const float* __restrict__ Sp, const float* __restrict__ Sn,
                                   const float* __restrict__ cntP, const float* __restrict__ cntN,
                                   const float* __restrict__ Wpd, const float* __restrict__ bpd,
                                   const float* __restrict__ Wnd, const float* __restrict__ bnd,
                                   float* __restrict__ Xmol, unsigned short* __restrict__ Xmb) {
  int n = blockIdx.x;
  int t = threadIdx.x;          // 0..127 ; wave0 computes h_pos2, wave1 h_neg2
  int w = t >> 6;
  int lane = t & 63;
  __shared__ float sh_op[128], sh_on[128], sh_h[128], sh_ss[2];
  float icp = 1.0f / (cntP[n] + 1.0f);
  float icn = 1.0f / (cntN[n] + 1.0f);
  float hv = H1[(size_t)n * 128 + t];
  sh_h[t]  = hv;
  sh_op[t] = (Sp[(size_t)n * 128 + t] + hv) * icp;   // mean incl. self-loop
  sh_on[t] = (Sn[(size_t)n * 128 + t] + hv) * icn;
  __syncthreads();
  const float* W = w ? Wnd : Wpd;
  float pre = (w ? bnd : bpd)[lane];
  int o1b = w ? 64 : 0;
  int o2b = w ? 0 : 64;
  for (int k = 0; k < 64; ++k) pre += sh_op[o1b + k] * W[k * 64 + lane];
  for (int k = 0; k < 64; ++k) pre += sh_on[o2b + k] * W[(64 + k) * 64 + lane];
  for (int k = 0; k < 64; ++k) pre += sh_h[w * 64 + k] * W[(128 + k) * 64 + lane];
  float ss = pre * pre;
#pragma unroll
  for (int o = 32; o > 0; o >>= 1) ss += __shfl_xor(ss, o);
  float tv = tanhf(pre / fmaxf(sqrtf(ss), 1e-12f));
  float ts = tv * tv;
#pragma unroll
  for (int o = 32; o > 0; o >>= 1) ts += __shfl_xor(ts, o);
  if (lane == 0) sh_ss[w] = ts;
  __syncthreads();
  float xm = tv / fmaxf(sqrtf(sh_ss[0] + sh_ss[1]), 1e-12f);
  Xmol[(size_t)n * 128 + t] = xm;
  Xmb[(size_t)n * 128 + t]  = f2bf(xm);
}

// ---- pred: (Xm @ Xm^T)*mask, LDS-staged coalesced epilogue -----------------
#define TPAD 68   // 64 + 4: rows 4 apart land 16 banks apart (2-way only)
__global__ void pred_kernel(const unsigned short* __restrict__ Xmb,
                            const float* __restrict__ mask,
                            const float* __restrict__ labels,
                            float* __restrict__ pred, float* __restrict__ lossAcc) {
  __shared__ float tile[64 * TPAD];
  int wave = threadIdx.x >> 6;
  int lane = threadIdx.x & 63;
  int row0 = blockIdx.x * 64 + wave * 16;
  int col0 = blockIdx.y * 64;
  int lrow = lane & 15;
  int koff = (lane >> 4) * 8;
  f32x4 acc[4] = {};
  const unsigned short* Ap = Xmb + (size_t)(row0 + lrow) * 128 + koff;
  const unsigned short* Bp = Xmb + (size_t)(col0 + lrow) * 128 + koff;
#pragma unroll
  for (int k0 = 0; k0 < 128; k0 += 32) {
    bf16x8 a = *reinterpret_cast<const bf16x8*>(Ap + k0);
#pragma unroll
    for (int c = 0; c < 4; ++c) {
      bf16x8 b = *reinterpret_cast<const bf16x8*>(Bp + (size_t)c * 16 * 128 + k0);
      acc[c] = __builtin_amdgcn_mfma_f32_16x16x32_bf16(a, b, acc[c], 0, 0, 0);
    }
  }
  // stage C tile (local rows = wave*16 + (lane>>4)*4 + r, cols = (lane&15) + c*16)
  int lr0 = wave * 16 + (lane >> 4) * 4;
  int lc0 = lane & 15;
#pragma unroll
  for (int c = 0; c < 4; ++c)
#pragma unroll
    for (int r = 0; r < 4; ++r)
      tile[(lr0 + r) * TPAD + lc0 + c * 16] = acc[c][r];
  __syncthreads();

  // coalesced epilogue: thread t handles float4 at flat = i*1024 + t*4
  float local = 0.0f;
  size_t base = (size_t)(blockIdx.x * 64) * N_NODES + blockIdx.y * 64;
#pragma unroll
  for (int i = 0; i < 4; ++i) {
    int flat = i * 1024 + threadIdx.x * 4;
    int rr = flat >> 6;
    int cc = flat & 63;
    size_t g = base + (size_t)rr * N_NODES + cc;
    f32x4 m = __builtin_nontemporal_load(reinterpret_cast<const f32x4*>(mask + g));
    f32x4 l = __builtin_nontemporal_load(reinterpret_cast<const f32x4*>(labels + g));
    const float* tp = &tile[rr * TPAD + cc];
    f32x4 p;
    p.x = tp[0] * m.x; p.y = tp[1] * m.y; p.z = tp[2] * m.z; p.w = tp[3] * m.w;
    __builtin_nontemporal_store(p, reinterpret_cast<f32x4*>(pred + g));
    f32x4 d = p - l;
    local += d.x * d.x + d.y * d.y + d.z * d.z + d.w * d.w;
  }
#pragma unroll
  for (int o = 32; o > 0; o >>= 1) local += __shfl_xor(local, o);
  __shared__ float red[4];
  if (lane == 0) red[wave] = local;
  __syncthreads();
  if (threadIdx.x == 0) atomicAdd(lossAcc, red[0] + red[1] + red[2] + red[3]);
}

__global__ void loss_final_kernel(const float* __restrict__ lossAcc, float* __restrict__ out0) {
  out0[0] = lossAcc[0] * (1.0f / ((float)N_NODES * (float)N_NODES));
}

extern "C" void kernel_launch(void* const* d_in, const int* in_sizes, int n_in,
                              void* d_out, int out_size, void* d_ws, size_t ws_size,
                              hipStream_t stream) {
  const float* X      = (const float*)d_in[0];
  const int*   pe     = (const int*)d_in[1];
  const int*   ne     = (const int*)d_in[2];
  const float* labels = (const float*)d_in[3];
  const float* mask   = (const float*)d_in[4];
  const float* Wpb    = (const float*)d_in[5];
  const float* bpb    = (const float*)d_in[6];
  const float* Wnb    = (const float*)d_in[7];
  const float* bnb    = (const float*)d_in[8];
  const float* Wpd    = (const float*)d_in[9];
  const float* bpd    = (const float*)d_in[10];
  const float* Wnd    = (const float*)d_in[11];
  const float* bnd    = (const float*)d_in[12];

  float* out      = (float*)d_out;
  float* out_xmol = out + 1;
  float* out_pred = out + 1 + (size_t)N_NODES * 128;

  char* ws = (char*)d_ws;
  size_t off = 0;
  float* Y = (float*)(ws + off);      off += (size_t)N_NODES * 256 * 4;
  char* zstart = ws + off;
  float* aggP = (float*)(ws + off);   off += (size_t)N_NODES * 64 * 4;
  float* aggN = (float*)(ws + off);   off += (size_t)N_NODES * 64 * 4;
  float* cntP = (float*)(ws + off);   off += (size_t)N_NODES * 4;
  float* cntN = (float*)(ws + off);   off += (size_t)N_NODES * 4;
  float* Sp   = (float*)(ws + off);   off += (size_t)N_NODES * 128 * 4;
  float* Sn   = (float*)(ws + off);   off += (size_t)N_NODES * 128 * 4;
  float* lossAcc = (float*)(ws + off); off += 256;
  size_t zsize = (size_t)((ws + off) - zstart);
  unsigned short* Xb  = (unsigned short*)(ws + off); off += (size_t)N_NODES * D_IN * 2;
  unsigned short* WT  = (unsigned short*)(ws + off); off += (size_t)256 * 2048 * 2;
  unsigned short* Xmb = (unsigned short*)(ws + off); off += (size_t)N_NODES * 128 * 2;
  float* H1 = (float*)(ws + off);     off += (size_t)N_NODES * 128 * 4;

  (void)hipMemsetAsync(zstart, 0, zsize, stream);
  cast_x_kernel<<<16000, 256, 0, stream>>>(X, Xb, N_NODES * D_IN / 4);
  packw_kernel<<<2048, 256, 0, stream>>>(Wpb, Wnb, WT);
  gemm1_kernel<<<dim3(125, 4), 256, 0, stream>>>(Xb, WT, Y);
  base_scatter_kernel<<<(2 * NE * 64) / 256, 256, 0, stream>>>(Y, pe, ne, aggP, aggN, cntP, cntN);
  base_finish_kernel<<<N_NODES, 128, 0, stream>>>(Y, aggP, aggN, cntP, cntN, bpb, bnb, H1);
  deep_scatter_kernel<<<(2 * NE * 128) / 256, 256, 0, stream>>>(H1, pe, ne, Sp, Sn);
  deep_finish_kernel<<<N_NODES, 128, 0, stream>>>(H1, Sp, Sn, cntP, cntN, Wpd, bpd, Wnd, bnd,
                                                  out_xmol, Xmb);
  pred_kernel<<<dim3(125, 125), 256, 0, stream>>>(Xmb, mask, labels, out_pred, lossAcc);
  loss_final_kernel<<<1, 1, 0, stream>>>(lossAcc, out);
}

// Round 4
// 418.637 us; speedup vs baseline: 1.4138x; 1.3011x over previous
//
#include <hip/hip_runtime.h>
#include <hip/hip_bf16.h>

#define N_NODES 8000
#define D_IN    2048
#define NE      100000

typedef __attribute__((ext_vector_type(8))) short bf16x8;
typedef __attribute__((ext_vector_type(4))) float f32x4;

__device__ inline unsigned short f2bf(float f) {
  union { float f; unsigned u; } v; v.f = f;
  unsigned r = v.u + 0x7fffu + ((v.u >> 16) & 1u);   // round-to-nearest-even
  return (unsigned short)(r >> 16);
}

// ---- pack W_pb/W_nb into transposed bf16 [256 cols][2048 k] ---------------
// cols 0:64 = Wpb agg ; 64:128 = Wpb self ; 128:192 = Wnb agg ; 192:256 = Wnb self
__global__ void packw_kernel(const float* __restrict__ Wpb,
                             const float* __restrict__ Wnb,
                             unsigned short* __restrict__ WT) {
  int idx = blockIdx.x * 256 + threadIdx.x;   // = c*2048 + k
  int c = idx >> 11;
  int k = idx & 2047;
  const float* W = (c < 128) ? Wpb : Wnb;
  int cc = c & 63;
  int kk = (c & 64) ? (2048 + k) : k;
  WT[idx] = f2bf(W[(size_t)kk * 64 + cc]);
}

// ---- GEMM1 (fused f32->bf16 cast): Y[8000][256] = bf16(X) @ Wpack ---------
// 500 blocks x 256 thr; all 4 waves share rows blockIdx*16 (A L1-reuse),
// wave w covers cols w*64..w*64+63 with acc[4].
__global__ void gemm1_kernel(const float* __restrict__ X,
                             const unsigned short* __restrict__ WT,
                             float* __restrict__ Y) {
  int wave = threadIdx.x >> 6;
  int lane = threadIdx.x & 63;
  int lrow = lane & 15;
  int koff = (lane >> 4) * 8;
  int row = blockIdx.x * 16 + lrow;
  int col0 = wave * 64;
  f32x4 acc[4] = {};
  const float* Ap = X + (size_t)row * D_IN + koff;
  const unsigned short* Bp = WT + (size_t)(col0 + lrow) * D_IN + koff;
  for (int k0 = 0; k0 < D_IN; k0 += 32) {
    f32x4 a0 = *reinterpret_cast<const f32x4*>(Ap + k0);
    f32x4 a1 = *reinterpret_cast<const f32x4*>(Ap + k0 + 4);
    bf16x8 af;
    af[0] = (short)f2bf(a0.x); af[1] = (short)f2bf(a0.y);
    af[2] = (short)f2bf(a0.z); af[3] = (short)f2bf(a0.w);
    af[4] = (short)f2bf(a1.x); af[5] = (short)f2bf(a1.y);
    af[6] = (short)f2bf(a1.z); af[7] = (short)f2bf(a1.w);
#pragma unroll
    for (int c = 0; c < 4; ++c) {
      bf16x8 b = *reinterpret_cast<const bf16x8*>(Bp + (size_t)c * 16 * D_IN + k0);
      acc[c] = __builtin_amdgcn_mfma_f32_16x16x32_bf16(af, b, acc[c], 0, 0, 0);
    }
  }
  int crow = blockIdx.x * 16 + (lane >> 4) * 4;
  int ccol = col0 + (lane & 15);
#pragma unroll
  for (int c = 0; c < 4; ++c)
#pragma unroll
    for (int r = 0; r < 4; ++r)
      Y[(size_t)(crow + r) * 256 + ccol + c * 16] = acc[c][r];
}

// ---- CSR build: count -> scan -> fill -------------------------------------
__global__ void count_kernel(const int* __restrict__ pe, const int* __restrict__ ne,
                             int* __restrict__ cntP, int* __restrict__ cntN) {
  int e = blockIdx.x * 256 + threadIdx.x;
  if (e < NE) atomicAdd(&cntP[pe[e]], 1);
  else if (e < 2 * NE) atomicAdd(&cntN[ne[e - NE]], 1);
}

__global__ void scan_kernel(const int* __restrict__ cntP, const int* __restrict__ cntN,
                            int* __restrict__ rpP, int* __restrict__ rpN) {
  const int* cnt = blockIdx.x ? cntN : cntP;
  int* rp = blockIdx.x ? rpN : rpP;
  __shared__ int s[1024];
  int t = threadIdx.x;
  int base = t * 8;
  int loc[8]; int tot = 0;
#pragma unroll
  for (int i = 0; i < 8; ++i) {
    int v = (base + i < N_NODES) ? cnt[base + i] : 0;
    loc[i] = tot; tot += v;
  }
  s[t] = tot; __syncthreads();
  for (int off = 1; off < 1024; off <<= 1) {
    int v = (t >= off) ? s[t - off] : 0;
    __syncthreads();
    s[t] += v;
    __syncthreads();
  }
  int pre = t ? s[t - 1] : 0;
#pragma unroll
  for (int i = 0; i < 8; ++i) {
    int idx = base + i;
    if (idx <= N_NODES) rp[idx] = pre + loc[i];
  }
}

__global__ void fill_kernel(const int* __restrict__ pe, const int* __restrict__ ne,
                            const int* __restrict__ rpP, const int* __restrict__ rpN,
                            int* __restrict__ curP, int* __restrict__ curN,
                            int* __restrict__ colP, int* __restrict__ colN) {
  int e = blockIdx.x * 256 + threadIdx.x;
  if (e < NE) {
    int r = pe[e];
    int pos = atomicAdd(&curP[r], 1);
    colP[rpP[r] + pos] = pe[NE + e];
  } else if (e < 2 * NE) {
    int ee = e - NE;
    int r = ne[ee];
    int pos = atomicAdd(&curN[r], 1);
    colN[rpN[r] + pos] = ne[NE + ee];
  }
}

// ---- base (pull): mean-agg + self + bias, l2norm, tanh -> H1 ---------------
__global__ void base_kernel(const float* __restrict__ Y,
                            const int* __restrict__ rpP, const int* __restrict__ colP,
                            const int* __restrict__ rpN, const int* __restrict__ colN,
                            const float* __restrict__ bpb, const float* __restrict__ bnb,
                            float* __restrict__ H1) {
  int n = blockIdx.x;
  int w = threadIdx.x >> 6;   // 0 = pos, 1 = neg
  int d = threadIdx.x & 63;
  const int* rp = w ? rpN : rpP;
  const int* ci = w ? colN : colP;
  int s0 = rp[n], e0 = rp[n + 1];
  int off = w ? 128 : 0;
  float sum = 0.0f;
  for (int i = s0; i < e0; ++i) sum += Y[(size_t)ci[i] * 256 + off + d];
  float pre = sum / fmaxf((float)(e0 - s0), 1.0f)
            + Y[(size_t)n * 256 + off + 64 + d] + (w ? bnb : bpb)[d];
  float ss = pre * pre;
#pragma unroll
  for (int o = 32; o > 0; o >>= 1) ss += __shfl_xor(ss, o);
  H1[(size_t)n * 128 + w * 64 + d] = tanhf(pre / fmaxf(sqrtf(ss), 1e-12f));
}

// ---- deep (pull): mean-agg over pe/ne + GEMV + l2norm + tanh + final norm --
__global__ void deep_kernel(const float* __restrict__ H1,
                            const int* __restrict__ rpP, const int* __restrict__ colP,
                            const int* __restrict__ rpN, const int* __restrict__ colN,
                            const float* __restrict__ Wpd, const float* __restrict__ bpd,
                            const float* __restrict__ Wnd, const float* __restrict__ bnd,
                            float* __restrict__ Xmol, unsigned short* __restrict__ Xmb) {
  int n = blockIdx.x;
  int t = threadIdx.x;          // 0..127 ; wave0 computes h_pos2, wave1 h_neg2
  int w = t >> 6;
  int lane = t & 63;
  __shared__ float sh_op[128], sh_on[128], sh_h[128], sh_ss[2];
  int sP = rpP[n], eP = rpP[n + 1];
  int sN = rpN[n], eN = rpN[n + 1];
  float sp = 0.0f, sn = 0.0f;
  for (int i = sP; i < eP; ++i) sp += H1[(size_t)colP[i] * 128 + t];
  for (int i = sN; i < eN; ++i) sn += H1[(size_t)colN[i] * 128 + t];
  float hv = H1[(size_t)n * 128 + t];
  sh_h[t]  = hv;
  sh_op[t] = (sp + hv) / (float)(eP - sP + 1);   // mean incl. self-loop
  sh_on[t] = (sn + hv) / (float)(eN - sN + 1);
  __syncthreads();
  const float* W = w ? Wnd : Wpd;
  float pre = (w ? bnd : bpd)[lane];
  int o1b = w ? 64 : 0;
  int o2b = w ? 0 : 64;
  for (int k = 0; k < 64; ++k) pre += sh_op[o1b + k] * W[k * 64 + lane];
  for (int k = 0; k < 64; ++k) pre += sh_on[o2b + k] * W[(64 + k) * 64 + lane];
  for (int k = 0; k < 64; ++k) pre += sh_h[w * 64 + k] * W[(128 + k) * 64 + lane];
  float ss = pre * pre;
#pragma unroll
  for (int o = 32; o > 0; o >>= 1) ss += __shfl_xor(ss, o);
  float tv = tanhf(pre / fmaxf(sqrtf(ss), 1e-12f));
  float ts = tv * tv;
#pragma unroll
  for (int o = 32; o > 0; o >>= 1) ts += __shfl_xor(ts, o);
  if (lane == 0) sh_ss[w] = ts;
  __syncthreads();
  float xm = tv / fmaxf(sqrtf(sh_ss[0] + sh_ss[1]), 1e-12f);
  Xmol[(size_t)n * 128 + t] = xm;
  Xmb[(size_t)n * 128 + t]  = f2bf(xm);
}

// ---- pred: (Xm @ Xm^T)*mask; x = col-tile (consecutive blocks stream
//      consecutive addresses), LDS-staged coalesced NT epilogue --------------
#define TPAD 68
__global__ void pred_kernel(const unsigned short* __restrict__ Xmb,
                            const float* __restrict__ mask,
                            const float* __restrict__ labels,
                            float* __restrict__ pred, float* __restrict__ lossAcc) {
  __shared__ float tile[64 * TPAD];
  int wave = threadIdx.x >> 6;
  int lane = threadIdx.x & 63;
  int row0 = blockIdx.y * 64 + wave * 16;
  int col0 = blockIdx.x * 64;
  int lrow = lane & 15;
  int koff = (lane >> 4) * 8;
  f32x4 acc[4] = {};
  const unsigned short* Ap = Xmb + (size_t)(row0 + lrow) * 128 + koff;
  const unsigned short* Bp = Xmb + (size_t)(col0 + lrow) * 128 + koff;
#pragma unroll
  for (int k0 = 0; k0 < 128; k0 += 32) {
    bf16x8 a = *reinterpret_cast<const bf16x8*>(Ap + k0);
#pragma unroll
    for (int c = 0; c < 4; ++c) {
      bf16x8 b = *reinterpret_cast<const bf16x8*>(Bp + (size_t)c * 16 * 128 + k0);
      acc[c] = __builtin_amdgcn_mfma_f32_16x16x32_bf16(a, b, acc[c], 0, 0, 0);
    }
  }
  int lr0 = wave * 16 + (lane >> 4) * 4;
  int lc0 = lane & 15;
#pragma unroll
  for (int c = 0; c < 4; ++c)
#pragma unroll
    for (int r = 0; r < 4; ++r)
      tile[(lr0 + r) * TPAD + lc0 + c * 16] = acc[c][r];
  __syncthreads();

  float local = 0.0f;
  size_t base = (size_t)(blockIdx.y * 64) * N_NODES + blockIdx.x * 64;
#pragma unroll
  for (int i = 0; i < 4; ++i) {
    int flat = i * 1024 + threadIdx.x * 4;
    int rr = flat >> 6;
    int cc = flat & 63;
    size_t g = base + (size_t)rr * N_NODES + cc;
    f32x4 m = __builtin_nontemporal_load(reinterpret_cast<const f32x4*>(mask + g));
    f32x4 l = __builtin_nontemporal_load(reinterpret_cast<const f32x4*>(labels + g));
    const float* tp = &tile[rr * TPAD + cc];
    f32x4 p;
    p.x = tp[0] * m.x; p.y = tp[1] * m.y; p.z = tp[2] * m.z; p.w = tp[3] * m.w;
    __builtin_nontemporal_store(p, reinterpret_cast<f32x4*>(pred + g));
    f32x4 d = p - l;
    local += d.x * d.x + d.y * d.y + d.z * d.z + d.w * d.w;
  }
#pragma unroll
  for (int o = 32; o > 0; o >>= 1) local += __shfl_xor(local, o);
  __shared__ float red[4];
  if (lane == 0) red[wave] = local;
  __syncthreads();
  if (threadIdx.x == 0) {
    int slot = (blockIdx.y * 125 + blockIdx.x) & 1023;
    atomicAdd(&lossAcc[slot], red[0] + red[1] + red[2] + red[3]);
  }
}

__global__ void loss_final_kernel(const float* __restrict__ lossAcc, float* __restrict__ out0) {
  int t = threadIdx.x;   // 1024
  float v = lossAcc[t];
#pragma unroll
  for (int o = 32; o > 0; o >>= 1) v += __shfl_xor(v, o);
  __shared__ float red[16];
  if ((t & 63) == 0) red[t >> 6] = v;
  __syncthreads();
  if (t == 0) {
    float s = 0;
    for (int i = 0; i < 16; ++i) s += red[i];
    out0[0] = s * (1.0f / ((float)N_NODES * (float)N_NODES));
  }
}

extern "C" void kernel_launch(void* const* d_in, const int* in_sizes, int n_in,
                              void* d_out, int out_size, void* d_ws, size_t ws_size,
                              hipStream_t stream) {
  const float* X      = (const float*)d_in[0];
  const int*   pe     = (const int*)d_in[1];
  const int*   ne     = (const int*)d_in[2];
  const float* labels = (const float*)d_in[3];
  const float* mask   = (const float*)d_in[4];
  const float* Wpb    = (const float*)d_in[5];
  const float* bpb    = (const float*)d_in[6];
  const float* Wnb    = (const float*)d_in[7];
  const float* bnb    = (const float*)d_in[8];
  const float* Wpd    = (const float*)d_in[9];
  const float* bpd    = (const float*)d_in[10];
  const float* Wnd    = (const float*)d_in[11];
  const float* bnd    = (const float*)d_in[12];

  float* out      = (float*)d_out;
  float* out_xmol = out + 1;
  float* out_pred = out + 1 + (size_t)N_NODES * 128;

  char* ws = (char*)d_ws;
  size_t off = 0;
  float* Y = (float*)(ws + off);             off += (size_t)N_NODES * 256 * 4;
  float* H1 = (float*)(ws + off);            off += (size_t)N_NODES * 128 * 4;
  unsigned short* WT = (unsigned short*)(ws + off);  off += (size_t)256 * 2048 * 2;
  unsigned short* Xmb = (unsigned short*)(ws + off); off += (size_t)N_NODES * 128 * 2;
  int* rpP  = (int*)(ws + off);              off += 8192 * 4;
  int* rpN  = (int*)(ws + off);              off += 8192 * 4;
  int* colP = (int*)(ws + off);              off += (size_t)NE * 4;
  int* colN = (int*)(ws + off);              off += (size_t)NE * 4;
  char* zstart = ws + off;
  int* cntPi = (int*)(ws + off);             off += (size_t)N_NODES * 4;
  int* cntNi = (int*)(ws + off);             off += (size_t)N_NODES * 4;
  int* curP  = (int*)(ws + off);             off += (size_t)N_NODES * 4;
  int* curN  = (int*)(ws + off);             off += (size_t)N_NODES * 4;
  float* lossAcc = (float*)(ws + off);       off += 1024 * 4;
  size_t zsize = (size_t)((ws + off) - zstart);

  (void)hipMemsetAsync(zstart, 0, zsize, stream);
  packw_kernel<<<2048, 256, 0, stream>>>(Wpb, Wnb, WT);
  gemm1_kernel<<<500, 256, 0, stream>>>(X, WT, Y);
  count_kernel<<<(2 * NE + 255) / 256, 256, 0, stream>>>(pe, ne, cntPi, cntNi);
  scan_kernel<<<2, 1024, 0, stream>>>(cntPi, cntNi, rpP, rpN);
  fill_kernel<<<(2 * NE + 255) / 256, 256, 0, stream>>>(pe, ne, rpP, rpN, curP, curN, colP, colN);
  base_kernel<<<N_NODES, 128, 0, stream>>>(Y, rpP, colP, rpN, colN, bpb, bnb, H1);
  deep_kernel<<<N_NODES, 128, 0, stream>>>(H1, rpP, colP, rpN, colN, Wpd, bpd, Wnd, bnd,
                                           out_xmol, Xmb);
  pred_kernel<<<dim3(125, 125), 256, 0, stream>>>(Xmb, mask, labels, out_pred, lossAcc);
  loss_final_kernel<<<1, 1024, 0, stream>>>(lossAcc, out);
}